// Round 3
// baseline (620.864 us; speedup 1.0000x reference)
//
#include <hip/hip_runtime.h>
#include <hip/hip_bf16.h>
#include <hip/hip_cooperative_groups.h>

namespace cg = cooperative_groups;

#define NROW 1024

struct Params {
    const float* x; const int* adj;
    const float* W1; const float* a1; const float* b1;
    const float* W2; const float* a2; const float* b2;
    const float* W3; const float* a3; const float* b3;
    const float* l1w; const float* l1b;
    const float* l2w; const float* l2b;
    const float* l3w; const float* l3b;
    float* out;
    float* h1; float* o1; float* h2; float* o2; float* h3; float* xf;
    float* e1b; float* t1g;
};

__device__ __forceinline__ float wave_reduce(float v) {
    for (int off = 32; off; off >>= 1) v += __shfl_down(v, off);
    return v;
}

// h[i,:] = in[i,:] @ W ; e1[i] = h[i,:] . a[:F].  R rows/block, F*R == 512 threads.
template <int K, int F, int R>
__device__ void gemm_e1_stage(const float* __restrict__ in, const float* __restrict__ W,
                              const float* __restrict__ a, float* __restrict__ h,
                              float* __restrict__ e1, int b, float* smem) {
    int i0 = b * R;
    if (i0 >= NROW) return;               // block-uniform guard
    float* srow = smem;                   // R*K
    float* red  = smem + R * K;           // 8
    int t = threadIdx.x;
    for (int idx = t; idx < R * K; idx += 512) srow[idx] = in[i0 * K + idx];
    __syncthreads();
    int c = t % F, r = t / F;
    const float* wp = W + c;
    const float* sp = srow + r * K;
    float acc0 = 0.f, acc1 = 0.f;
#pragma unroll 4
    for (int k = 0; k < K; k += 2) {
        acc0 = fmaf(sp[k], wp[k * F], acc0);
        acc1 = fmaf(sp[k + 1], wp[(k + 1) * F], acc1);
    }
    float acc = acc0 + acc1;
    h[(i0 + r) * F + c] = acc;
    float p = wave_reduce(acc * a[c]);
    int lane = t & 63, wv = t >> 6;
    if (lane == 0) red[wv] = p;
    __syncthreads();
    constexpr int WPR = F / 64;
    if (t < R) {
        float s = 0.f;
#pragma unroll
        for (int w = 0; w < WPR; ++w) s += red[t * WPR + w];
        e1[i0 + t] = s;
    }
    __syncthreads();
}

// Fused E2-row + wexp + masked row-sums (ballot masks) + att@h + relu+bias+relu.
// 4 output rows per block, 512 threads.
template <int F, int G>
__device__ void attn_stage(const float* __restrict__ h, const int* __restrict__ adj,
                           const float* __restrict__ e1, const float* __restrict__ a,
                           const float* __restrict__ bb, float* __restrict__ outp,
                           int b, float* smem) {
    constexpr int NQ = 512 / F;
    float* wexp_sh = smem;                 // 1024
    float* E2row   = smem + 1024;          // F
    float* cred    = smem + 1152;          // 2048
    float* redf    = smem + 3200;          // 8
    float* sinv    = smem + 3208;          // 4
    unsigned long long* msk = (unsigned long long*)(smem + 3216); // 4*16 u64
    int t = threadIdx.x;
    int i0 = b * 4;
    int ib = i0 / F;
    // E2 row (parallel over all 8 waves): E2[c] = sum_p a[F+p] * h[(p*G+ib)*F + c]
    {
        int g = t / F, c = t % F;
        float acc = 0.f;
#pragma unroll 4
        for (int p = g; p < F; p += NQ) acc = fmaf(a[F + p], h[(p * G + ib) * F + c], acc);
        cred[t] = acc;
    }
    __syncthreads();
    if (t < F) {
        float s = 0.f;
#pragma unroll
        for (int g = 0; g < NQ; ++g) s += cred[g * F + t];
        E2row[t] = s;
    }
    __syncthreads();
    for (int j = t; j < NROW; j += 512) {
        float v = e1[j] + E2row[j & (F - 1)];
        v = v > 0.f ? v : 0.2f * v;
        wexp_sh[j] = expf(v);
    }
    __syncthreads();
    int lane = t & 63, wv = t >> 6;
    {
        int r = wv & 3;
        const int* arow = adj + (size_t)(i0 + r) * NROW;
        float s = 0.f;
        for (int jb = (wv >> 2); jb < 16; jb += 2) {
            int j = jb * 64 + lane;
            bool on = arow[j] > 0;
            unsigned long long m = __ballot(on);
            if (lane == 0) msk[r * 16 + jb] = m;
            s += on ? wexp_sh[j] : 0.f;
        }
        s = wave_reduce(s);
        if (lane == 0) redf[wv] = s;
    }
    __syncthreads();
    if (t < 4) sinv[t] = 1.f / (redf[t] + redf[t + 4]);
    __syncthreads();
    int c = t % F, q = t / F;
    float acc0 = 0.f, acc1 = 0.f, acc2 = 0.f, acc3 = 0.f;
    const unsigned long long* m0 = msk;
    const unsigned long long* m1 = msk + 16;
    const unsigned long long* m2 = msk + 32;
    const unsigned long long* m3 = msk + 48;
    for (int jb = 0; jb < 16; ++jb) {
        unsigned long long k0 = m0[jb] >> q, k1 = m1[jb] >> q,
                           k2 = m2[jb] >> q, k3 = m3[jb] >> q;
#pragma unroll
        for (int ss = 0; ss < 64 / NQ; ++ss) {
            int j = jb * 64 + q + ss * NQ;
            float w = wexp_sh[j];
            float hv = h[j * F + c];
            acc0 = fmaf((k0 & 1) ? w : 0.f, hv, acc0);
            acc1 = fmaf((k1 & 1) ? w : 0.f, hv, acc1);
            acc2 = fmaf((k2 & 1) ? w : 0.f, hv, acc2);
            acc3 = fmaf((k3 & 1) ? w : 0.f, hv, acc3);
            k0 >>= NQ; k1 >>= NQ; k2 >>= NQ; k3 >>= NQ;
        }
    }
    float* cr = cred + t * 4;
    cr[0] = acc0; cr[1] = acc1; cr[2] = acc2; cr[3] = acc3;
    __syncthreads();
    if (t < 4 * F) {
        int rr = t / F, cc = t % F;
        float tot = 0.f;
#pragma unroll
        for (int qq = 0; qq < NQ; ++qq) tot += cred[(qq * F + cc) * 4 + rr];
        float v = tot * sinv[rr];
        v = v > 0.f ? v : 0.f;
        v += bb[cc];
        v = v > 0.f ? v : 0.f;
        outp[(i0 + rr) * F + cc] = v;
    }
    __syncthreads();
}

// head layer 1: 6 rows per block; x chunk loaded once per iteration, 6 w-streams.
__device__ void head1_stage(const float* __restrict__ l1w, const float* __restrict__ l1b,
                            const float* __restrict__ xf, float* __restrict__ t1g,
                            int b, float* smem) {
    float* redH = smem;  // 8 waves * 6 rows
    int t = threadIdx.x;
    const float4* xv = (const float4*)xf;
    const float4* w0 = (const float4*)l1w + (size_t)(b * 6 + 0) * 16384;
    const float4* w1 = (const float4*)l1w + (size_t)(b * 6 + 1) * 16384;
    const float4* w2 = (const float4*)l1w + (size_t)(b * 6 + 2) * 16384;
    const float4* w3 = (const float4*)l1w + (size_t)(b * 6 + 3) * 16384;
    const float4* w4 = (const float4*)l1w + (size_t)(b * 6 + 4) * 16384;
    const float4* w5 = (const float4*)l1w + (size_t)(b * 6 + 5) * 16384;
    float acc[6] = {0.f, 0.f, 0.f, 0.f, 0.f, 0.f};
#pragma unroll 2
    for (int u = 0; u < 32; ++u) {
        int idx = t + u * 512;
        float4 xx = xv[idx];
        float4 a0 = w0[idx], a1 = w1[idx], a2 = w2[idx],
               a3 = w3[idx], a4 = w4[idx], a5 = w5[idx];
        acc[0] = fmaf(a0.x, xx.x, fmaf(a0.y, xx.y, fmaf(a0.z, xx.z, fmaf(a0.w, xx.w, acc[0]))));
        acc[1] = fmaf(a1.x, xx.x, fmaf(a1.y, xx.y, fmaf(a1.z, xx.z, fmaf(a1.w, xx.w, acc[1]))));
        acc[2] = fmaf(a2.x, xx.x, fmaf(a2.y, xx.y, fmaf(a2.z, xx.z, fmaf(a2.w, xx.w, acc[2]))));
        acc[3] = fmaf(a3.x, xx.x, fmaf(a3.y, xx.y, fmaf(a3.z, xx.z, fmaf(a3.w, xx.w, acc[3]))));
        acc[4] = fmaf(a4.x, xx.x, fmaf(a4.y, xx.y, fmaf(a4.z, xx.z, fmaf(a4.w, xx.w, acc[4]))));
        acc[5] = fmaf(a5.x, xx.x, fmaf(a5.y, xx.y, fmaf(a5.z, xx.z, fmaf(a5.w, xx.w, acc[5]))));
    }
    int lane = t & 63, wv = t >> 6;
#pragma unroll
    for (int rl = 0; rl < 6; ++rl) {
        float p = wave_reduce(acc[rl]);
        if (lane == 0) redH[wv * 6 + rl] = p;
    }
    __syncthreads();
    if (t < 6) {
        int row = b * 6 + t;
        float s = l1b[row];
#pragma unroll
        for (int w = 0; w < 8; ++w) s += redH[w * 6 + t];
        t1g[row] = s > 0.f ? s : 0.f;
    }
    __syncthreads();
}

__device__ void head23_stage(const float* __restrict__ l2w, const float* __restrict__ l2b,
                             const float* __restrict__ l3w, const float* __restrict__ l3b,
                             const float* __restrict__ t1g, float* __restrict__ outp,
                             int b, float* smem) {
    float* t1s = smem;         // 256
    float* red = smem + 3200;  // 2
    int t = threadIdx.x;
    for (int r = t; r < 256; r += 512) t1s[r] = t1g[b * 256 + r];
    __syncthreads();
    if (t < 128) {
        const float* wrow = l2w + (size_t)(b * 128 + t) * 256;
        float a0 = 0.f, a1 = 0.f;
#pragma unroll 8
        for (int k = 0; k < 256; k += 2) {
            a0 = fmaf(wrow[k], t1s[k], a0);
            a1 = fmaf(wrow[k + 1], t1s[k + 1], a1);
        }
        float acc = a0 + a1 + l2b[b * 128 + t];
        float t2 = 1.f / (1.f + expf(-acc));
        float p = wave_reduce(l3w[b * 128 + t] * t2);
        if ((t & 63) == 0) red[t >> 6] = p;
    }
    __syncthreads();
    if (t == 0) outp[b] = red[0] + red[1] + l3b[b];
}

__global__ void __launch_bounds__(512) gat_mega(Params p) {
    __shared__ float smem[3392];
    cg::grid_group grid = cg::this_grid();
    int b = blockIdx.x;

    gemm_e1_stage<512, 128, 4>(p.x, p.W1, p.a1, p.h1, p.e1b, b, smem);
    __threadfence(); grid.sync();
    attn_stage<128, 8>(p.h1, p.adj, p.e1b, p.a1, p.b1, p.o1, b, smem);
    __threadfence(); grid.sync();
    gemm_e1_stage<128, 64, 8>(p.o1, p.W2, p.a2, p.h2, p.e1b, b, smem);
    __threadfence(); grid.sync();
    attn_stage<64, 16>(p.h2, p.adj, p.e1b, p.a2, p.b2, p.o2, b, smem);
    __threadfence(); grid.sync();
    gemm_e1_stage<64, 64, 8>(p.o2, p.W3, p.a3, p.h3, p.e1b, b, smem);
    __threadfence(); grid.sync();
    attn_stage<64, 16>(p.h3, p.adj, p.e1b, p.a3, p.b3, p.xf, b, smem);
    __threadfence(); grid.sync();
    head1_stage(p.l1w, p.l1b, p.xf, p.t1g, b, smem);
    __threadfence(); grid.sync();
    if (b < 6) head23_stage(p.l2w, p.l2b, p.l3w, p.l3b, p.t1g, p.out, b, smem);
}

extern "C" void kernel_launch(void* const* d_in, const int* in_sizes, int n_in,
                              void* d_out, int out_size, void* d_ws, size_t ws_size,
                              hipStream_t stream) {
    float* ws = (float*)d_ws;
    Params p;
    p.x   = (const float*)d_in[0];
    p.adj = (const int*)d_in[1];
    p.W1  = (const float*)d_in[2];
    p.a1  = (const float*)d_in[3];
    p.b1  = (const float*)d_in[4];
    p.W2  = (const float*)d_in[5];
    p.a2  = (const float*)d_in[6];
    p.b2  = (const float*)d_in[7];
    p.W3  = (const float*)d_in[8];
    p.a3  = (const float*)d_in[9];
    p.b3  = (const float*)d_in[10];
    p.l1w = (const float*)d_in[11];
    p.l1b = (const float*)d_in[12];
    p.l2w = (const float*)d_in[13];
    p.l2b = (const float*)d_in[14];
    p.l3w = (const float*)d_in[15];
    p.l3b = (const float*)d_in[16];
    p.out = (float*)d_out;
    p.h1  = ws;            // 1024*128
    p.o1  = ws + 131072;   // 1024*128
    p.h2  = ws + 262144;   // 1024*64
    p.o2  = ws + 327680;   // 1024*64
    p.h3  = ws + 393216;   // 1024*64
    p.xf  = ws + 458752;   // 1024*64
    p.e1b = ws + 524288;   // 1024
    p.t1g = ws + 525312;   // 1536

    void* args[] = {&p};
    hipLaunchCooperativeKernel((const void*)gat_mega, dim3(256), dim3(512), args, 0, stream);
}

// Round 4
// 244.161 us; speedup vs baseline: 2.5429x; 2.5429x over previous
//
#include <hip/hip_runtime.h>
#include <hip/hip_bf16.h>

#define NROW 1024

__device__ __forceinline__ float wave_reduce(float v) {
    for (int off = 32; off; off >>= 1) v += __shfl_down(v, off);
    return v;
}

// Stage 1: h[i,:] = in[i,:] @ W ; e1[i] = h[i,:] . a[:F].  R rows/block, F*R == 512.
template <int K, int F, int R>
__global__ void __launch_bounds__(512) gemm_e1_kernel(const float* __restrict__ in,
                                                      const float* __restrict__ W,
                                                      const float* __restrict__ a,
                                                      float* __restrict__ h,
                                                      float* __restrict__ e1) {
    __shared__ float srow[R * K];
    __shared__ float red[8];
    int t = threadIdx.x;
    int i0 = blockIdx.x * R;
    for (int idx = t; idx < R * K; idx += 512) srow[idx] = in[i0 * K + idx];
    __syncthreads();
    int c = t % F, r = t / F;
    const float* wp = W + c;
    const float* sp = srow + r * K;
    float acc0 = 0.f, acc1 = 0.f;
#pragma unroll 4
    for (int k = 0; k < K; k += 2) {
        acc0 = fmaf(sp[k], wp[(size_t)k * F], acc0);
        acc1 = fmaf(sp[k + 1], wp[(size_t)(k + 1) * F], acc1);
    }
    float acc = acc0 + acc1;
    h[(i0 + r) * F + c] = acc;
    float p = wave_reduce(acc * a[c]);
    int lane = t & 63, wv = t >> 6;
    if (lane == 0) red[wv] = p;
    __syncthreads();
    constexpr int WPR = F / 64;
    if (t < R) {
        float s = 0.f;
#pragma unroll
        for (int w = 0; w < WPR; ++w) s += red[t * WPR + w];
        e1[i0 + t] = s;
    }
}

// Attention core: E2 row + wexp + ballot masks + row sums + att@h + relu+bias+relu.
// Leaves the 4 output rows (4*F floats) in orow (LDS). 512 threads, 4 rows/block.
template <int F, int G>
__device__ __forceinline__ void attn_core(const float* __restrict__ h,
                                          const int* __restrict__ adj,
                                          const float* __restrict__ e1in,
                                          const float* __restrict__ aprev,
                                          const float* __restrict__ bprev, int i0,
                                          float* wexp_sh, float* E2row, float* cred,
                                          float* redf, float* sinv,
                                          unsigned long long* msk, float* orow) {
    constexpr int NQ = 512 / F;
    int t = threadIdx.x;
    int ib = i0 / F;
    {
        int g = t / F, c = t % F;
        float acc = 0.f;
#pragma unroll 4
        for (int p = g; p < F; p += NQ) acc = fmaf(aprev[F + p], h[(p * G + ib) * F + c], acc);
        cred[t] = acc;
    }
    __syncthreads();
    if (t < F) {
        float s = 0.f;
#pragma unroll
        for (int g = 0; g < NQ; ++g) s += cred[g * F + t];
        E2row[t] = s;
    }
    __syncthreads();
    for (int j = t; j < NROW; j += 512) {
        float v = e1in[j] + E2row[j & (F - 1)];
        v = v > 0.f ? v : 0.2f * v;
        wexp_sh[j] = expf(v);
    }
    __syncthreads();
    int lane = t & 63, wv = t >> 6;
    {
        int r = wv & 3;
        const int* arow = adj + (size_t)(i0 + r) * NROW;
        float s = 0.f;
        for (int jb = (wv >> 2); jb < 16; jb += 2) {
            int j = jb * 64 + lane;
            bool on = arow[j] > 0;
            unsigned long long m = __ballot(on);
            if (lane == 0) msk[r * 16 + jb] = m;
            s += on ? wexp_sh[j] : 0.f;
        }
        s = wave_reduce(s);
        if (lane == 0) redf[wv] = s;
    }
    __syncthreads();
    if (t < 4) sinv[t] = 1.f / (redf[t] + redf[t + 4]);
    __syncthreads();
    int c = t % F, q = t / F;
    float acc0 = 0.f, acc1 = 0.f, acc2 = 0.f, acc3 = 0.f;
    const unsigned long long* m0 = msk;
    const unsigned long long* m1 = msk + 16;
    const unsigned long long* m2 = msk + 32;
    const unsigned long long* m3 = msk + 48;
    for (int jb = 0; jb < 16; ++jb) {
        unsigned long long k0 = m0[jb] >> q, k1 = m1[jb] >> q,
                           k2 = m2[jb] >> q, k3 = m3[jb] >> q;
#pragma unroll
        for (int ss = 0; ss < 64 / NQ; ++ss) {
            int j = jb * 64 + q + ss * NQ;
            float w = wexp_sh[j];
            float hv = h[j * F + c];
            acc0 = fmaf((k0 & 1) ? w : 0.f, hv, acc0);
            acc1 = fmaf((k1 & 1) ? w : 0.f, hv, acc1);
            acc2 = fmaf((k2 & 1) ? w : 0.f, hv, acc2);
            acc3 = fmaf((k3 & 1) ? w : 0.f, hv, acc3);
            k0 >>= NQ; k1 >>= NQ; k2 >>= NQ; k3 >>= NQ;
        }
    }
    float* cr = cred + t * 4;
    cr[0] = acc0; cr[1] = acc1; cr[2] = acc2; cr[3] = acc3;
    __syncthreads();
    if (t < 4 * F) {
        int rr = t / F, cc = t % F;
        float tot = 0.f;
#pragma unroll
        for (int qq = 0; qq < NQ; ++qq) tot += cred[(qq * F + cc) * 4 + rr];
        float v = tot * sinv[rr];
        v = v > 0.f ? v : 0.f;
        v += bprev[cc];
        v = v > 0.f ? v : 0.f;
        orow[rr * F + cc] = v;
    }
    __syncthreads();
}

// Stages 2,3: attn layer + next-layer gemm (row-local) fused. FN must be 64.
template <int F, int G, int FN>
__global__ void __launch_bounds__(512) attn_gemm_kernel(
    const float* __restrict__ h, const int* __restrict__ adj,
    const float* __restrict__ e1in, const float* __restrict__ aprev,
    const float* __restrict__ bprev, const float* __restrict__ Wn,
    const float* __restrict__ an, float* __restrict__ hout,
    float* __restrict__ e1out) {
    __shared__ float wexp_sh[1024];
    __shared__ float E2row[F];
    __shared__ float cred[2048];
    __shared__ float redf[8];
    __shared__ float sinv[4];
    __shared__ float orow[4 * F];
    __shared__ unsigned long long msk[64];
    int i0 = blockIdx.x * 4;
    attn_core<F, G>(h, adj, e1in, aprev, bprev, i0, wexp_sh, E2row, cred, redf, sinv, msk, orow);
    int t = threadIdx.x;
    if (t < 4 * FN) {
        int r = t / FN, c = t % FN;
        float acc = 0.f;
#pragma unroll 8
        for (int k = 0; k < F; ++k) acc = fmaf(orow[r * F + k], Wn[k * FN + c], acc);
        hout[(i0 + r) * FN + c] = acc;
        float p = wave_reduce(acc * an[c]);  // FN==64 -> wave index == r
        if ((t & 63) == 0) redf[r] = p;
    }
    __syncthreads();
    if (t < 4) e1out[i0 + t] = redf[t];
}

// Stage 4: attn layer 3 + head layer-1 partial dot products over this block's
// 256-element xf chunk. part[row*256 + b] = l1w[row, b*256:(b+1)*256] . xf_chunk
template <int F, int G>
__global__ void __launch_bounds__(512) attn_head_kernel(
    const float* __restrict__ h, const int* __restrict__ adj,
    const float* __restrict__ e1in, const float* __restrict__ aprev,
    const float* __restrict__ bprev, const float* __restrict__ l1w,
    float* __restrict__ part) {
    __shared__ float wexp_sh[1024];
    __shared__ float E2row[F];
    __shared__ float cred[2048];
    __shared__ float redf[8];
    __shared__ float sinv[4];
    __shared__ float xch[256];
    __shared__ unsigned long long msk[64];
    int b = blockIdx.x;
    int i0 = b * 4;
    attn_core<F, G>(h, adj, e1in, aprev, bprev, i0, wexp_sh, E2row, cred, redf, sinv, msk, xch);
    int t = threadIdx.x, lane = t & 63, wv = t >> 6;
    float4 x4 = ((const float4*)xch)[lane];
    const float4* wbase = (const float4*)l1w + (size_t)b * 64 + lane;
    for (int r = wv; r < 1536; r += 32) {
        float4 w0 = wbase[(size_t)r * 16384];
        float4 w1 = wbase[(size_t)(r + 8) * 16384];
        float4 w2 = wbase[(size_t)(r + 16) * 16384];
        float4 w3 = wbase[(size_t)(r + 24) * 16384];
        float p0 = fmaf(w0.x, x4.x, fmaf(w0.y, x4.y, fmaf(w0.z, x4.z, w0.w * x4.w)));
        float p1 = fmaf(w1.x, x4.x, fmaf(w1.y, x4.y, fmaf(w1.z, x4.z, w1.w * x4.w)));
        float p2 = fmaf(w2.x, x4.x, fmaf(w2.y, x4.y, fmaf(w2.z, x4.z, w2.w * x4.w)));
        float p3 = fmaf(w3.x, x4.x, fmaf(w3.y, x4.y, fmaf(w3.z, x4.z, w3.w * x4.w)));
        p0 = wave_reduce(p0);
        p1 = wave_reduce(p1);
        p2 = wave_reduce(p2);
        p3 = wave_reduce(p3);
        if (lane == 0) {
            part[(size_t)r * 256 + b] = p0;
            part[(size_t)(r + 8) * 256 + b] = p1;
            part[(size_t)(r + 16) * 256 + b] = p2;
            part[(size_t)(r + 24) * 256 + b] = p3;
        }
    }
}

// Stage 5: reduce partials -> t1 (relu), then head layers 2 (sigmoid) + 3.
__global__ void __launch_bounds__(256) head23_kernel(
    const float* __restrict__ part, const float* __restrict__ l1b,
    const float* __restrict__ l2w, const float* __restrict__ l2b,
    const float* __restrict__ l3w, const float* __restrict__ l3b,
    float* __restrict__ out) {
    __shared__ float t1s[256];
    __shared__ float t2s[128];
    int hh = blockIdx.x, t = threadIdx.x, lane = t & 63, wv = t >> 6;
    for (int rr = wv; rr < 256; rr += 4) {
        int row = hh * 256 + rr;
        float4 p4 = ((const float4*)(part + (size_t)row * 256))[lane];
        float p = (p4.x + p4.y) + (p4.z + p4.w);
        p = wave_reduce(p);
        if (lane == 0) {
            float s = p + l1b[row];
            t1s[rr] = s > 0.f ? s : 0.f;
        }
    }
    __syncthreads();
    float4 tv = ((const float4*)t1s)[lane];
    for (int o = wv; o < 128; o += 4) {
        float4 w4 = ((const float4*)(l2w + ((size_t)hh * 128 + o) * 256))[lane];
        float p = fmaf(w4.x, tv.x, fmaf(w4.y, tv.y, fmaf(w4.z, tv.z, w4.w * tv.w)));
        p = wave_reduce(p);
        if (lane == 0) {
            float acc = p + l2b[hh * 128 + o];
            t2s[o] = 1.f / (1.f + expf(-acc));
        }
    }
    __syncthreads();
    if (wv == 0) {
        float p = l3w[hh * 128 + lane] * t2s[lane] +
                  l3w[hh * 128 + 64 + lane] * t2s[64 + lane];
        p = wave_reduce(p);
        if (lane == 0) out[hh] = p + l3b[hh];
    }
}

extern "C" void kernel_launch(void* const* d_in, const int* in_sizes, int n_in,
                              void* d_out, int out_size, void* d_ws, size_t ws_size,
                              hipStream_t stream) {
    const float* x   = (const float*)d_in[0];
    const int*   adj = (const int*)d_in[1];
    const float* W1  = (const float*)d_in[2];
    const float* a1  = (const float*)d_in[3];
    const float* b1  = (const float*)d_in[4];
    const float* W2  = (const float*)d_in[5];
    const float* a2  = (const float*)d_in[6];
    const float* b2  = (const float*)d_in[7];
    const float* W3  = (const float*)d_in[8];
    const float* a3  = (const float*)d_in[9];
    const float* b3  = (const float*)d_in[10];
    const float* l1w = (const float*)d_in[11];
    const float* l1b = (const float*)d_in[12];
    const float* l2w = (const float*)d_in[13];
    const float* l2b = (const float*)d_in[14];
    const float* l3w = (const float*)d_in[15];
    const float* l3b = (const float*)d_in[16];
    float* out = (float*)d_out;

    float* ws = (float*)d_ws;
    float* h1   = ws;            // 1024*128
    float* h2   = ws + 131072;   // 1024*64
    float* h3   = ws + 196608;   // 1024*64
    float* e1a  = ws + 262144;   // 1024
    float* e1b  = ws + 263168;   // 1024
    float* e1c  = ws + 264192;   // 1024
    float* part = ws + 265216;   // 1536*256

    gemm_e1_kernel<512, 128, 4><<<256, 512, 0, stream>>>(x, W1, a1, h1, e1a);
    attn_gemm_kernel<128, 8, 64><<<256, 512, 0, stream>>>(h1, adj, e1a, a1, b1, W2, a2, h2, e1b);
    attn_gemm_kernel<64, 16, 64><<<256, 512, 0, stream>>>(h2, adj, e1b, a2, b2, W3, a3, h3, e1c);
    attn_head_kernel<64, 16><<<256, 512, 0, stream>>>(h3, adj, e1c, a3, b3, l1w, part);
    head23_kernel<<<6, 256, 0, stream>>>(part, l1b, l2w, l2b, l3w, l3b, out);
}

// Round 5
// 162.994 us; speedup vs baseline: 3.8091x; 1.4980x over previous
//
#include <hip/hip_runtime.h>
#include <hip/hip_bf16.h>

#define NROW 1024

typedef float f4v __attribute__((ext_vector_type(4)));

__device__ __forceinline__ float wave_reduce(float v) {
    for (int off = 32; off; off >>= 1) v += __shfl_down(v, off);
    return v;
}

// Stage 1: h[i,:] = in[i,:] @ W ; e1[i] = h[i,:] . a[:F].  R rows/block, F*R == 512.
template <int K, int F, int R>
__global__ void __launch_bounds__(512) gemm_e1_kernel(const float* __restrict__ in,
                                                      const float* __restrict__ W,
                                                      const float* __restrict__ a,
                                                      float* __restrict__ h,
                                                      float* __restrict__ e1) {
    __shared__ float srow[R * K];
    __shared__ float red[8];
    int t = threadIdx.x;
    int i0 = blockIdx.x * R;
    for (int idx = t; idx < R * K; idx += 512) srow[idx] = in[i0 * K + idx];
    __syncthreads();
    int c = t % F, r = t / F;
    const float* wp = W + c;
    const float* sp = srow + r * K;
    float acc0 = 0.f, acc1 = 0.f;
#pragma unroll 4
    for (int k = 0; k < K; k += 2) {
        acc0 = fmaf(sp[k], wp[(size_t)k * F], acc0);
        acc1 = fmaf(sp[k + 1], wp[(size_t)(k + 1) * F], acc1);
    }
    float acc = acc0 + acc1;
    h[(i0 + r) * F + c] = acc;
    float p = wave_reduce(acc * a[c]);
    int lane = t & 63, wv = t >> 6;
    if (lane == 0) red[wv] = p;
    __syncthreads();
    constexpr int WPR = F / 64;
    if (t < R) {
        float s = 0.f;
#pragma unroll
        for (int w = 0; w < WPR; ++w) s += red[t * WPR + w];
        e1[i0 + t] = s;
    }
}

// Attention core: E2 row + wexp + ballot masks + row sums + att@h + relu+bias+relu.
// Leaves the 4 output rows (4*F floats) in orow (LDS). 512 threads, 4 rows/block.
template <int F, int G>
__device__ __forceinline__ void attn_core(const float* __restrict__ h,
                                          const int* __restrict__ adj,
                                          const float* __restrict__ e1in,
                                          const float* __restrict__ aprev,
                                          const float* __restrict__ bprev, int i0,
                                          float* wexp_sh, float* E2row, float* cred,
                                          float* redf, float* sinv,
                                          unsigned long long* msk, float* orow) {
    constexpr int NQ = 512 / F;
    int t = threadIdx.x;
    int ib = i0 / F;
    {
        int g = t / F, c = t % F;
        float acc = 0.f;
#pragma unroll 4
        for (int p = g; p < F; p += NQ) acc = fmaf(aprev[F + p], h[(p * G + ib) * F + c], acc);
        cred[t] = acc;
    }
    __syncthreads();
    if (t < F) {
        float s = 0.f;
#pragma unroll
        for (int g = 0; g < NQ; ++g) s += cred[g * F + t];
        E2row[t] = s;
    }
    __syncthreads();
    for (int j = t; j < NROW; j += 512) {
        float v = e1in[j] + E2row[j & (F - 1)];
        v = v > 0.f ? v : 0.2f * v;
        wexp_sh[j] = expf(v);
    }
    __syncthreads();
    int lane = t & 63, wv = t >> 6;
    {
        int r = wv & 3;
        const int* arow = adj + (size_t)(i0 + r) * NROW;
        float s = 0.f;
        for (int jb = (wv >> 2); jb < 16; jb += 2) {
            int j = jb * 64 + lane;
            bool on = arow[j] > 0;
            unsigned long long m = __ballot(on);
            if (lane == 0) msk[r * 16 + jb] = m;
            s += on ? wexp_sh[j] : 0.f;
        }
        s = wave_reduce(s);
        if (lane == 0) redf[wv] = s;
    }
    __syncthreads();
    if (t < 4) sinv[t] = 1.f / (redf[t] + redf[t + 4]);
    __syncthreads();
    int c = t % F, q = t / F;
    float acc0 = 0.f, acc1 = 0.f, acc2 = 0.f, acc3 = 0.f;
    const unsigned long long* m0 = msk;
    const unsigned long long* m1 = msk + 16;
    const unsigned long long* m2 = msk + 32;
    const unsigned long long* m3 = msk + 48;
    for (int jb = 0; jb < 16; ++jb) {
        unsigned long long k0 = m0[jb] >> q, k1 = m1[jb] >> q,
                           k2 = m2[jb] >> q, k3 = m3[jb] >> q;
#pragma unroll
        for (int ss = 0; ss < 64 / NQ; ++ss) {
            int j = jb * 64 + q + ss * NQ;
            float w = wexp_sh[j];
            float hv = h[j * F + c];
            acc0 = fmaf((k0 & 1) ? w : 0.f, hv, acc0);
            acc1 = fmaf((k1 & 1) ? w : 0.f, hv, acc1);
            acc2 = fmaf((k2 & 1) ? w : 0.f, hv, acc2);
            acc3 = fmaf((k3 & 1) ? w : 0.f, hv, acc3);
            k0 >>= NQ; k1 >>= NQ; k2 >>= NQ; k3 >>= NQ;
        }
    }
    float* cr = cred + t * 4;
    cr[0] = acc0; cr[1] = acc1; cr[2] = acc2; cr[3] = acc3;
    __syncthreads();
    if (t < 4 * F) {
        int rr = t / F, cc = t % F;
        float tot = 0.f;
#pragma unroll
        for (int qq = 0; qq < NQ; ++qq) tot += cred[(qq * F + cc) * 4 + rr];
        float v = tot * sinv[rr];
        v = v > 0.f ? v : 0.f;
        v += bprev[cc];
        v = v > 0.f ? v : 0.f;
        orow[rr * F + cc] = v;
    }
    __syncthreads();
}

// Stages 2,3: attn layer + next-layer gemm (row-local) fused. FN must be 64.
template <int F, int G, int FN>
__global__ void __launch_bounds__(512) attn_gemm_kernel(
    const float* __restrict__ h, const int* __restrict__ adj,
    const float* __restrict__ e1in, const float* __restrict__ aprev,
    const float* __restrict__ bprev, const float* __restrict__ Wn,
    const float* __restrict__ an, float* __restrict__ hout,
    float* __restrict__ e1out) {
    __shared__ float wexp_sh[1024];
    __shared__ float E2row[F];
    __shared__ float cred[2048];
    __shared__ float redf[8];
    __shared__ float sinv[4];
    __shared__ float orow[4 * F];
    __shared__ unsigned long long msk[64];
    int i0 = blockIdx.x * 4;
    attn_core<F, G>(h, adj, e1in, aprev, bprev, i0, wexp_sh, E2row, cred, redf, sinv, msk, orow);
    int t = threadIdx.x;
    if (t < 4 * FN) {
        int r = t / FN, c = t % FN;
        float acc = 0.f;
#pragma unroll 8
        for (int k = 0; k < F; ++k) acc = fmaf(orow[r * F + k], Wn[k * FN + c], acc);
        hout[(i0 + r) * FN + c] = acc;
        float p = wave_reduce(acc * an[c]);  // FN==64 -> wave index == r
        if ((t & 63) == 0) redf[r] = p;
    }
    __syncthreads();
    if (t < 4) e1out[i0 + t] = redf[t];
}

// Stage 4: attn layer 3 -> xf (global)
template <int F, int G>
__global__ void __launch_bounds__(512) attn_xf_kernel(
    const float* __restrict__ h, const int* __restrict__ adj,
    const float* __restrict__ e1in, const float* __restrict__ aprev,
    const float* __restrict__ bprev, float* __restrict__ xf) {
    __shared__ float wexp_sh[1024];
    __shared__ float E2row[F];
    __shared__ float cred[2048];
    __shared__ float redf[8];
    __shared__ float sinv[4];
    __shared__ float orow[4 * F];
    __shared__ unsigned long long msk[64];
    int i0 = blockIdx.x * 4;
    attn_core<F, G>(h, adj, e1in, aprev, bprev, i0, wexp_sh, E2row, cred, redf, sinv, msk, orow);
    int t = threadIdx.x;
    if (t < 4 * F) xf[(size_t)i0 * F + t] = orow[t];
}

// Stage 5: head layer 1. 2 rows per block, 768 blocks x 512 threads (3 blocks/CU).
// l1w loaded nontemporally (streamed once, don't evict xf from L2).
__global__ void __launch_bounds__(512) head1_kernel(const float* __restrict__ l1w,
                                                    const float* __restrict__ l1b,
                                                    const float* __restrict__ xf,
                                                    float* __restrict__ t1g) {
    __shared__ float red[16];
    int t = threadIdx.x;
    int r0 = blockIdx.x * 2;
    const f4v* xv = (const f4v*)xf;
    const f4v* w0p = (const f4v*)l1w + (size_t)r0 * 16384;
    const f4v* w1p = w0p + 16384;
    float acc0 = 0.f, acc1 = 0.f;
#pragma unroll 4
    for (int it = t; it < 16384; it += 512) {
        f4v xx = xv[it];
        f4v w0 = __builtin_nontemporal_load(&w0p[it]);
        f4v w1 = __builtin_nontemporal_load(&w1p[it]);
        acc0 = fmaf(w0.x, xx.x, fmaf(w0.y, xx.y, fmaf(w0.z, xx.z, fmaf(w0.w, xx.w, acc0))));
        acc1 = fmaf(w1.x, xx.x, fmaf(w1.y, xx.y, fmaf(w1.z, xx.z, fmaf(w1.w, xx.w, acc1))));
    }
    acc0 = wave_reduce(acc0);
    acc1 = wave_reduce(acc1);
    int lane = t & 63, wv = t >> 6;
    if (lane == 0) { red[wv * 2] = acc0; red[wv * 2 + 1] = acc1; }
    __syncthreads();
    if (t < 2) {
        int row = r0 + t;
        float s = l1b[row];
#pragma unroll
        for (int w = 0; w < 8; ++w) s += red[w * 2 + t];
        t1g[row] = s > 0.f ? s : 0.f;
    }
}

// Stage 6: head layers 2 (sigmoid) + 3. 6 blocks x 256 threads.
__global__ void __launch_bounds__(256) head23_kernel(
    const float* __restrict__ t1g, const float* __restrict__ l2w,
    const float* __restrict__ l2b, const float* __restrict__ l3w,
    const float* __restrict__ l3b, float* __restrict__ out) {
    __shared__ float t1s[256];
    __shared__ float t2s[128];
    int hh = blockIdx.x, t = threadIdx.x, lane = t & 63, wv = t >> 6;
    t1s[t] = t1g[hh * 256 + t];
    __syncthreads();
    float4 tv = ((const float4*)t1s)[lane];
    for (int o = wv; o < 128; o += 4) {
        float4 w4 = ((const float4*)(l2w + ((size_t)hh * 128 + o) * 256))[lane];
        float p = fmaf(w4.x, tv.x, fmaf(w4.y, tv.y, fmaf(w4.z, tv.z, w4.w * tv.w)));
        p = wave_reduce(p);
        if (lane == 0) t2s[o] = 1.f / (1.f + expf(-(p + l2b[hh * 128 + o])));
    }
    __syncthreads();
    if (wv == 0) {
        float p = l3w[hh * 128 + lane] * t2s[lane] +
                  l3w[hh * 128 + 64 + lane] * t2s[64 + lane];
        p = wave_reduce(p);
        if (lane == 0) out[hh] = p + l3b[hh];
    }
}

extern "C" void kernel_launch(void* const* d_in, const int* in_sizes, int n_in,
                              void* d_out, int out_size, void* d_ws, size_t ws_size,
                              hipStream_t stream) {
    const float* x   = (const float*)d_in[0];
    const int*   adj = (const int*)d_in[1];
    const float* W1  = (const float*)d_in[2];
    const float* a1  = (const float*)d_in[3];
    const float* b1  = (const float*)d_in[4];
    const float* W2  = (const float*)d_in[5];
    const float* a2  = (const float*)d_in[6];
    const float* b2  = (const float*)d_in[7];
    const float* W3  = (const float*)d_in[8];
    const float* a3  = (const float*)d_in[9];
    const float* b3  = (const float*)d_in[10];
    const float* l1w = (const float*)d_in[11];
    const float* l1b = (const float*)d_in[12];
    const float* l2w = (const float*)d_in[13];
    const float* l2b = (const float*)d_in[14];
    const float* l3w = (const float*)d_in[15];
    const float* l3b = (const float*)d_in[16];
    float* out = (float*)d_out;

    float* ws = (float*)d_ws;
    float* h1   = ws;            // 1024*128
    float* h2   = ws + 131072;   // 1024*64
    float* h3   = ws + 196608;   // 1024*64
    float* xf   = ws + 262144;   // 1024*64
    float* e1a  = ws + 327680;   // 1024
    float* e1b  = ws + 328704;   // 1024
    float* e1c  = ws + 329728;   // 1024
    float* t1g  = ws + 330752;   // 1536

    gemm_e1_kernel<512, 128, 4><<<256, 512, 0, stream>>>(x, W1, a1, h1, e1a);
    attn_gemm_kernel<128, 8, 64><<<256, 512, 0, stream>>>(h1, adj, e1a, a1, b1, W2, a2, h2, e1b);
    attn_gemm_kernel<64, 16, 64><<<256, 512, 0, stream>>>(h2, adj, e1b, a2, b2, W3, a3, h3, e1c);
    attn_xf_kernel<64, 16><<<256, 512, 0, stream>>>(h3, adj, e1c, a3, b3, xf);
    head1_kernel<<<768, 512, 0, stream>>>(l1w, l1b, xf, t1g);
    head23_kernel<<<6, 256, 0, stream>>>(t1g, l2w, l2b, l3w, l3b, out);
}